// Round 5
// baseline (497.915 us; speedup 1.0000x reference)
//
#include <hip/hip_runtime.h>
#include <math.h>

typedef __attribute__((ext_vector_type(8))) short bf16x8;
typedef __attribute__((ext_vector_type(4))) float f32x4;

#define B_   2
#define L_   2048
#define D_   1024
#define H_   16
#define HD_  64
#define EPS_ 1e-3f
#define ML   (B_*L_)            // 4096 rows
#define NBIG 4096               // QKVG fused width (floats)
#define PU   8192               // QKVG row pitch in ushorts

// Per-head packed bf16 sub-buffers inside QKVG's own fp32 regions.
// Head h's packed data lives EXACTLY inside head h's fp32 region, so
// in-place conversion is block-local (read-all -> barrier -> write-all).
//   Q region (ushort   0..2047): Qh at h*128+0..63,        Ql at h*128+64..127
//   K region (ushort 2048..4095): Kh at 2048+h*128+0..63,  Kl at +64
//   V region (ushort 4096..6143): Yh at 4096+h*128+0..63,  Yl at +64
//     (V fp32 is dead after postproc stages it into Vth/Vtl)
//   G region (float 3072..4095) stays fp32 until retention epilogue.
#define OQ(h)  ((h) * 128)
#define OK_(h) (2048 + (h) * 128)
#define OY(h)  (4096 + (h) * 128)

#define MFMA(a,b,c) __builtin_amdgcn_mfma_f32_16x16x32_bf16((a),(b),(c),0,0,0)

// RNE split: f ~= hi + lo, both bf16 (round-to-nearest-even), err ~2^-17|f|
__device__ __forceinline__ void rsplit(float f, unsigned short& hi, unsigned short& lo) {
    unsigned int u = __float_as_uint(f);
    unsigned int r = u + (0x7fffu + ((u >> 16) & 1u));
    hi = (unsigned short)(r >> 16);
    float fh = __uint_as_float((unsigned int)(r & 0xffff0000u));
    float fl = f - fh;                       // exact (Sterbenz)
    unsigned int ul = __float_as_uint(fl);
    unsigned int rl = ul + (0x7fffu + ((ul >> 16) & 1u));
    lo = (unsigned short)(rl >> 16);
}

__device__ __forceinline__ void gload16(const unsigned short* src, unsigned short* lds) {
    __builtin_amdgcn_global_load_lds(
        (const __attribute__((address_space(1))) unsigned int*)src,
        (__attribute__((address_space(3))) unsigned int*)lds, 16, 0, 0);
}

// ---------------------------------------------------------------------------
// Weights: fp32 [K][N] -> transposed bf16 hi/lo WT[w][n][k]. grid = 5*256.
// ---------------------------------------------------------------------------
__global__ __launch_bounds__(256) void conv_weights(
        const float* __restrict__ W0, const float* __restrict__ W1,
        const float* __restrict__ W2, const float* __restrict__ W3,
        const float* __restrict__ W4,
        unsigned short* __restrict__ WTh, unsigned short* __restrict__ WTl) {
    __shared__ float tile[64][65];
    const int bx = blockIdx.x;
    const int w  = bx >> 8;
    const int tn = bx & 255;
    const int k0 = (tn >> 4) * 64;
    const int n0 = (tn & 15) * 64;
    const float* W = (w == 0) ? W0 : (w == 1) ? W1 : (w == 2) ? W2
                   : (w == 3) ? W3 : W4;
    const int t = threadIdx.x;
#pragma unroll
    for (int p = 0; p < 16; p++) {
        int idx = p * 256 + t;
        int r = idx >> 6, c = idx & 63;
        tile[r][c] = W[(size_t)(k0 + r) * 1024 + n0 + c];
    }
    __syncthreads();
#pragma unroll
    for (int p = 0; p < 16; p++) {
        int idx = p * 256 + t;
        int r = idx >> 6, c = idx & 63;
        float v = tile[c][r];                 // = W[k0+c][n0+r]
        size_t o = (size_t)(w * 1024 + n0 + r) * 1024 + k0 + c;
        unsigned short hb, lb;
        rsplit(v, hb, lb);
        WTh[o] = hb; WTl[o] = lb;
    }
}

// ---------------------------------------------------------------------------
// x fp32 -> xh/xl bf16. grid = 4096.
// ---------------------------------------------------------------------------
__global__ __launch_bounds__(256) void conv_x(const float* __restrict__ x,
        unsigned short* __restrict__ xh, unsigned short* __restrict__ xl) {
    size_t idx = (size_t)(blockIdx.x * 256 + threadIdx.x) * 4;
    float4 v = *(const float4*)&x[idx];
    ushort4 h, lo;
    rsplit(v.x, h.x, lo.x); rsplit(v.y, h.y, lo.y);
    rsplit(v.z, h.z, lo.z); rsplit(v.w, h.w, lo.w);
    *(ushort4*)&xh[idx] = h;
    *(ushort4*)&xl[idx] = lo;
}

// ---------------------------------------------------------------------------
// Split-bf16 GEMM with global_load_lds staging (m97 2-barrier structure).
// C[M][N] fp32 = (Ah+Al)[M][K] @ (Bh+Bl)^T, B stored transposed [N][K].
// BM=BN=128, BK=32, 256 thr = 4 waves (2x2). Linear LDS, wave w stages array w.
// ---------------------------------------------------------------------------
__global__ __launch_bounds__(256) void gemm_ldst(
        const unsigned short* __restrict__ Ah, const unsigned short* __restrict__ Al,
        const unsigned short* __restrict__ Bh, const unsigned short* __restrict__ Bl,
        float* __restrict__ C, int M, int N, int K, int gx) {
    __shared__ unsigned short SMEM[4][128 * 32];

    const int tid = threadIdx.x;
    const int l = tid & 63, w = tid >> 6;
    const int lg = l >> 4, lr = l & 15;
    const int wr = w >> 1, wc = w & 1;

    // XCD-aware swizzle (nwg % 8 == 0)
    const int cpx = gridDim.x >> 3;
    const int flat = blockIdx.x;
    const int swz = (flat & 7) * cpx + (flat >> 3);
    const int bm = (swz / gx) * 128, bn = (swz % gx) * 128;

    const unsigned short* arr = (w == 0) ? Ah : (w == 1) ? Al : (w == 2) ? Bh : Bl;
    const int rbase = (w < 2) ? bm : bn;
    const unsigned short* src0 = arr + (size_t)(rbase + (l >> 2)) * K + (l & 3) * 8;

    f32x4 acc[4][4];
#pragma unroll
    for (int mb = 0; mb < 4; mb++)
#pragma unroll
        for (int nb = 0; nb < 4; nb++) acc[mb][nb] = (f32x4){0.f, 0.f, 0.f, 0.f};

    for (int k0 = 0; k0 < K; k0 += 32) {
        __syncthreads();                 // readers done with LDS
#pragma unroll
        for (int i = 0; i < 8; i++)
            gload16(src0 + (size_t)i * 16 * K + k0, &SMEM[w][i * 512]);
        __syncthreads();                 // compiler drains vmcnt before barrier

        bf16x8 bhf[4], blf[4];
#pragma unroll
        for (int nb = 0; nb < 4; nb++) {
            bhf[nb] = *(const bf16x8*)&SMEM[2][(wc * 64 + nb * 16 + lr) * 32 + lg * 8];
            blf[nb] = *(const bf16x8*)&SMEM[3][(wc * 64 + nb * 16 + lr) * 32 + lg * 8];
        }
#pragma unroll
        for (int mb = 0; mb < 4; mb++) {
            bf16x8 ahf = *(const bf16x8*)&SMEM[0][(wr * 64 + mb * 16 + lr) * 32 + lg * 8];
            bf16x8 alf = *(const bf16x8*)&SMEM[1][(wr * 64 + mb * 16 + lr) * 32 + lg * 8];
#pragma unroll
            for (int nb = 0; nb < 4; nb++) {
                f32x4 a = acc[mb][nb];
                a = MFMA(ahf, bhf[nb], a);
                a = MFMA(ahf, blf[nb], a);
                a = MFMA(alf, bhf[nb], a);
                acc[mb][nb] = a;
            }
        }
    }

#pragma unroll
    for (int mb = 0; mb < 4; mb++)
#pragma unroll
        for (int r = 0; r < 4; r++) {
            size_t row = (size_t)(bm + wr * 64 + mb * 16 + lg * 4 + r);
#pragma unroll
            for (int nb = 0; nb < 4; nb++)
                C[row * N + bn + wc * 64 + nb * 16 + lr] = acc[mb][nb][r];
        }
}

// ---------------------------------------------------------------------------
// postproc: per (head, 64-row) tile: (a) V fp32 -> transposed split Vth/Vtl,
// (b) RoPE(Q,K) -> per-head packed bf16 written into head h's OWN Q/K fp32
// regions (block-local in-place: all reads before the barrier, all writes
// after). grid = 1024 (bh*32 + st).
// ---------------------------------------------------------------------------
__global__ __launch_bounds__(256) void postproc(float* __restrict__ QKVG,
        unsigned short* __restrict__ Vth, unsigned short* __restrict__ Vtl) {
    __shared__ float T[64][65];
    const int bid = blockIdx.x;
    const int bh = bid >> 5, st = bid & 31;
    const int b = bh >> 4, h = bh & (H_ - 1);
    const int t = threadIdx.x;
    const int row0 = b * L_ + st * 64;
    const int hcol = h * HD_;
    unsigned short* U = (unsigned short*)QKVG;

    const int seq = t >> 2;              // 0..63 (row within tile)
    const int dd0 = (t & 3) * 8;         // quarter of the 32 rope pairs

    // ---- phase 1a: V fp32 -> LDS transposed ----
    {
        const int cb = (t & 3) * 16;
        const float* p = QKVG + (size_t)(row0 + seq) * NBIG + 2048 + hcol + cb;
#pragma unroll
        for (int f = 0; f < 4; f++) {
            float4 v = *(const float4*)(p + f * 4);
            T[cb + f * 4 + 0][seq] = v.x;
            T[cb + f * 4 + 1][seq] = v.y;
            T[cb + f * 4 + 2][seq] = v.z;
            T[cb + f * 4 + 3][seq] = v.w;
        }
    }

    // ---- phase 1b: Q,K fp32 + rope into regs ----
    float qo1[8], qo2[8], ko1[8], ko2[8];
    {
        const float* pq = QKVG + (size_t)(row0 + seq) * NBIG + hcol;
        const float* pk = pq + 1024;
        float4 qa = *(const float4*)(pq + dd0);      float4 qb = *(const float4*)(pq + dd0 + 4);
        float4 qc = *(const float4*)(pq + dd0 + 32); float4 qd = *(const float4*)(pq + dd0 + 36);
        float4 ka = *(const float4*)(pk + dd0);      float4 kb = *(const float4*)(pk + dd0 + 4);
        float4 kc = *(const float4*)(pk + dd0 + 32); float4 kd = *(const float4*)(pk + dd0 + 36);
        float q1[8] = {qa.x,qa.y,qa.z,qa.w, qb.x,qb.y,qb.z,qb.w};
        float q2[8] = {qc.x,qc.y,qc.z,qc.w, qd.x,qd.y,qd.z,qd.w};
        float k1[8] = {ka.x,ka.y,ka.z,ka.w, kb.x,kb.y,kb.z,kb.w};
        float k2[8] = {kc.x,kc.y,kc.z,kc.w, kd.x,kd.y,kd.z,kd.w};
        const float C1 = 0.41524101186092029f;       // log2(10000)/32
        const int tp = st * 64 + seq;                // position within sequence
#pragma unroll
        for (int j = 0; j < 8; j++) {
            float ang = (float)tp * exp2f(-(float)(dd0 + j) * C1);
            float s_, c_;
            sincosf(ang, &s_, &c_);
            qo1[j] = q1[j] * c_ - q2[j] * s_;  qo2[j] = q2[j] * c_ + q1[j] * s_;
            ko1[j] = k1[j] * c_ - k2[j] * s_;  ko2[j] = k2[j] * c_ + k1[j] * s_;
        }
    }
    __syncthreads();     // ALL fp32 reads done before any in-place writes

    // ---- phase 2a: V splits from LDS -> Vth/Vtl [bh][d][seq] ----
    {
        const int d = t >> 2, sb = (t & 3) * 16;
        bf16x8 hv[2], lv[2];
#pragma unroll
        for (int f = 0; f < 16; f++) {
            unsigned short hb, lb;
            rsplit(T[d][sb + f], hb, lb);
            hv[f >> 3][f & 7] = (short)hb;
            lv[f >> 3][f & 7] = (short)lb;
        }
        size_t o = ((size_t)bh * HD_ + d) * L_ + st * 64 + sb;
        *(bf16x8*)&Vth[o] = hv[0]; *(bf16x8*)&Vth[o + 8] = hv[1];
        *(bf16x8*)&Vtl[o] = lv[0]; *(bf16x8*)&Vtl[o + 8] = lv[1];
    }

    // ---- phase 2b: rope splits -> head h's own Q/K regions ----
    {
        size_t rb = (size_t)(row0 + seq) * PU;
        bf16x8 v_[8];
#pragma unroll
        for (int j = 0; j < 8; j++) {
            unsigned short hb, lb;
            rsplit(qo1[j], hb, lb); v_[0][j] = (short)hb; v_[1][j] = (short)lb;
            rsplit(qo2[j], hb, lb); v_[2][j] = (short)hb; v_[3][j] = (short)lb;
            rsplit(ko1[j], hb, lb); v_[4][j] = (short)hb; v_[5][j] = (short)lb;
            rsplit(ko2[j], hb, lb); v_[6][j] = (short)hb; v_[7][j] = (short)lb;
        }
        *(bf16x8*)&U[rb + OQ(h)  + dd0]       = v_[0];   // Q dims 0..31  hi
        *(bf16x8*)&U[rb + OQ(h)  + 64 + dd0]  = v_[1];   //               lo
        *(bf16x8*)&U[rb + OQ(h)  + 32 + dd0]  = v_[2];   // Q dims 32..63 hi
        *(bf16x8*)&U[rb + OQ(h)  + 96 + dd0]  = v_[3];   //               lo
        *(bf16x8*)&U[rb + OK_(h) + dd0]       = v_[4];
        *(bf16x8*)&U[rb + OK_(h) + 64 + dd0]  = v_[5];
        *(bf16x8*)&U[rb + OK_(h) + 32 + dd0]  = v_[6];
        *(bf16x8*)&U[rb + OK_(h) + 96 + dd0]  = v_[7];
    }
}

// ---------------------------------------------------------------------------
// Retention v3: barrier-free, wave-balanced. 512 blocks x 256 thr.
// Wave g handles q-strips (ps, 127-ps) of 16 rows for one (b,h): exactly
// 33 k-tiles. K/V fragments read straight from global (L2-resident, pre-split,
// V pre-transposed). Only S round-trips through wave-private LDS.
// Epilogue: GroupNorm + SiLU gate -> Yh/Yl packed into head h's V region.
// ---------------------------------------------------------------------------
__global__ __launch_bounds__(256) void retention_v3(
        float* __restrict__ QKVG,
        const unsigned short* __restrict__ Vth, const unsigned short* __restrict__ Vtl,
        const float* __restrict__ gng, const float* __restrict__ gnb) {
    __shared__ unsigned short Ssh[4][16][72];
    __shared__ unsigned short Ssl[4][16][72];

    unsigned short* U = (unsigned short*)QKVG;
    const int tid = threadIdx.x;
    const int w = tid >> 6, l = tid & 63;
    const int lg = l >> 4, lr = l & 15;

    // bh-grouped XCD swizzle: XCD x gets bh in [4x, 4x+4)
    const int bsw = ((blockIdx.x & 7) << 6) | (blockIdx.x >> 3);
    const int g = bsw * 4 + w;            // 0..2047
    const int bh = g >> 6;                // 0..31
    const int ps = g & 63;                // strip pair (ps, 127-ps)
    const int b = bh >> 4, h = bh & (H_ - 1);
    const size_t rowb = (size_t)b * L_;
    const int hcol = h * HD_;
    const float l2g = log2f(1.f - exp2f(-(float)(5 + h)));

    float cfl[4];
#pragma unroll
    for (int jb = 0; jb < 4; jb++)
        cfl[jb] = exp2f(-l2g * (float)(16 * jb + lr));

#pragma unroll 1
    for (int half = 0; half < 2; half++) {
        const int s = half ? (127 - ps) : ps;
        const int rowq = s * 16;
        const int ktiles = (s >> 2) + 1;

        float rq[4];
#pragma unroll
        for (int r = 0; r < 4; r++)
            rq[r] = 0.125f * exp2f(l2g * (float)(rowq + lg * 4 + r));

        bf16x8 qfh[2], qfl[2];
        {
            size_t qo = (rowb + rowq + lr) * PU + OQ(h);
            qfh[0] = *(const bf16x8*)&U[qo + lg * 8];
            qfh[1] = *(const bf16x8*)&U[qo + 32 + lg * 8];
            qfl[0] = *(const bf16x8*)&U[qo + 64 + lg * 8];
            qfl[1] = *(const bf16x8*)&U[qo + 96 + lg * 8];
        }

        f32x4 o4[4];
#pragma unroll
        for (int db = 0; db < 4; db++) o4[db] = (f32x4){0.f, 0.f, 0.f, 0.f};

        for (int kt = 0; kt < ktiles; kt++) {
            const float ckt = exp2f(-l2g * (float)(kt * 64));
            float rqt[4];
#pragma unroll
            for (int r = 0; r < 4; r++) rqt[r] = rq[r] * ckt;
            const bool lastt = (kt == ktiles - 1);

            // ---- S = Q K^T (K frags straight from global) ----
            f32x4 s4[4];
#pragma unroll
            for (int jb = 0; jb < 4; jb++) {
                size_t ko = (rowb + kt * 64 + jb * 16 + lr) * PU + OK_(h);
                bf16x8 k0h = *(const bf16x8*)&U[ko + lg * 8];
                bf16x8 k1h = *(const bf16x8*)&U[ko + 32 + lg * 8];
                bf16x8 k0l = *(const bf16x8*)&U[ko + 64 + lg * 8];
                bf16x8 k1l = *(const bf16x8*)&U[ko + 96 + lg * 8];
                f32x4 sv = (f32x4){0.f, 0.f, 0.f, 0.f};
                sv = MFMA(qfh[0], k0h, sv);
                sv = MFMA(qfh[1], k1h, sv);
                sv = MFMA(qfh[0], k0l, sv);
                sv = MFMA(qfh[1], k1l, sv);
                sv = MFMA(qfl[0], k0h, sv);
                sv = MFMA(qfl[1], k1h, sv);
                s4[jb] = sv;
            }

            // ---- decay * mask * split -> LDS ----
#pragma unroll
            for (int jb = 0; jb < 4; jb++) {
#pragma unroll
                for (int r = 0; r < 4; r++) {
                    float sv = s4[jb][r] * rqt[r] * cfl[jb];
                    if (lastt) {
                        int qi = rowq + lg * 4 + r;
                        int kj = kt * 64 + jb * 16 + lr;
                        sv = (kj > qi) ? 0.f : sv;
                    }
                    unsigned short sh_, sl_;
                    rsplit(sv, sh_, sl_);
                    Ssh[w][lg * 4 + r][jb * 16 + lr] = sh_;
                    Ssl[w][lg * 4 + r][jb * 16 + lr] = sl_;
                }
            }

            // ---- O += S V (S frags from LDS, V frags from global) ----
            bf16x8 sfh[2], sfl[2];
            sfh[0] = *(const bf16x8*)&Ssh[w][lr][lg * 8];
            sfh[1] = *(const bf16x8*)&Ssh[w][lr][32 + lg * 8];
            sfl[0] = *(const bf16x8*)&Ssl[w][lr][lg * 8];
            sfl[1] = *(const bf16x8*)&Ssl[w][lr][32 + lg * 8];
#pragma unroll
            for (int db = 0; db < 4; db++) {
                size_t vo = ((size_t)bh * HD_ + db * 16 + lr) * L_ + kt * 64;
                bf16x8 v0h = *(const bf16x8*)&Vth[vo + lg * 8];
                bf16x8 v1h = *(const bf16x8*)&Vth[vo + 32 + lg * 8];
                bf16x8 v0l = *(const bf16x8*)&Vtl[vo + lg * 8];
                bf16x8 v1l = *(const bf16x8*)&Vtl[vo + 32 + lg * 8];
                f32x4 a = o4[db];
                a = MFMA(sfh[0], v0h, a);
                a = MFMA(sfh[1], v1h, a);
                a = MFMA(sfh[0], v0l, a);
                a = MFMA(sfh[1], v1l, a);
                a = MFMA(sfl[0], v0h, a);
                a = MFMA(sfl[1], v1h, a);
                o4[db] = a;
            }
        }

        // ---- GroupNorm (per row over 64 dims) + SiLU gate -> Yh/Yl ----
        float sum_[4], sq_[4];
#pragma unroll
        for (int r = 0; r < 4; r++) {
            float s_ = 0.f, q_ = 0.f;
#pragma unroll
            for (int db = 0; db < 4; db++) { float v = o4[db][r]; s_ += v; q_ += v * v; }
            sum_[r] = s_; sq_[r] = q_;
        }
#pragma unroll
        for (int m = 1; m < 16; m <<= 1) {
#pragma unroll
            for (int r = 0; r < 4; r++) {
                sum_[r] += __shfl_xor(sum_[r], m, 64);
                sq_[r]  += __shfl_xor(sq_[r], m, 64);
            }
        }
#pragma unroll
        for (int r = 0; r < 4; r++) {
            float mean = sum_[r] * (1.f / 64.f);
            float var  = sq_[r] * (1.f / 64.f) - mean * mean;
            float rstd = rsqrtf(var + EPS_);
            size_t row = rowb + rowq + lg * 4 + r;
#pragma unroll
            for (int db = 0; db < 4; db++) {
                int c = db * 16 + lr;
                float gv = QKVG[row * NBIG + 3072 + hcol + c];
                float y = (o4[db][r] - mean) * rstd * gng[hcol + c] + gnb[hcol + c];
                float sig = 1.f / (1.f + expf(-gv));
                float res = y * gv * sig;
                unsigned short hb, lb;
                rsplit(res, hb, lb);
                U[row * PU + OY(h) + c]      = hb;
                U[row * PU + OY(h) + 64 + c] = lb;
            }
        }
    }
}

// ---------------------------------------------------------------------------
// Out GEMM: BM=64, BN=128, BK=32, reg-staged. A = per-head-packed Y inside
// QKVG (element e of a row: off = 4096 + (e>>6)*128 + (e&63), lo at +64).
// 512 blocks (2/CU).
// ---------------------------------------------------------------------------
__global__ __launch_bounds__(256) void gemm_out64(
        const unsigned short* __restrict__ U,
        const unsigned short* __restrict__ Bh, const unsigned short* __restrict__ Bl,
        float* __restrict__ C) {
    __shared__ unsigned short As_h[64][40], As_l[64][40];
    __shared__ unsigned short Bs_h[128][40], Bs_l[128][40];
    const int K = 1024, N = 1024;

    const int tid = threadIdx.x;
    const int l = tid & 63, w = tid >> 6;
    const int lg = l >> 4, lr = l & 15;
    const int wr = w >> 1, wc = w & 1;

    const int flat = blockIdx.x;                       // 512 blocks
    const int swz = (flat & 7) * 64 + (flat >> 3);
    const int bm = (swz >> 3) * 64, bn = (swz & 7) * 128;

    f32x4 acc[2][4];
#pragma unroll
    for (int mb = 0; mb < 2; mb++)
#pragma unroll
        for (int nb = 0; nb < 4; nb++) acc[mb][nb] = (f32x4){0.f, 0.f, 0.f, 0.f};

    const int arow = tid >> 2, acol = (tid & 3) * 8;   // 64 rows x 32
    const int brow = tid >> 1, bcol = (tid & 1) * 16;  // 128 rows x 32

    for (int k0 = 0; k0 < K; k0 += 32) {
        const int e0 = k0 + acol;
        const size_t aoff = (size_t)(bm + arow) * PU + 4096
                          + ((e0 >> 6) << 7) + (e0 & 63);
        bf16x8 a_h = *(const bf16x8*)&U[aoff];
        bf16x8 a_l = *(const bf16x8*)&U[aoff + 64];
        bf16x8 b_h0 = *(const bf16x8*)&Bh[(size_t)(bn + brow) * K + k0 + bcol];
        bf16x8 b_h1 = *(const bf16x8*)&Bh[(size_t)(bn + brow) * K + k0 + bcol + 8];
        bf16x8 b_l0 = *(const bf16x8*)&Bl[(size_t)(bn + brow) * K + k0 + bcol];
        bf16x8 b_l1 = *(const bf16x8*)&Bl[(size_t)(bn + brow) * K + k0 + bcol + 8];

        __syncthreads();
        *(bf16x8*)&As_h[arow][acol] = a_h;
        *(bf16x8*)&As_l[arow][acol] = a_l;
        *(bf16x8*)&Bs_h[brow][bcol] = b_h0; *(bf16x8*)&Bs_h[brow][bcol + 8] = b_h1;
        *(bf16x8*)&Bs_l[brow][bcol] = b_l0; *(bf16x8*)&Bs_l[brow][bcol + 8] = b_l1;
        __syncthreads();

        bf16x8 bhf[4], blf[4];
#pragma unroll
        for (int nb = 0; nb < 4; nb++) {
            bhf[nb] = *(const bf16x8*)&Bs_h[wc * 64 + nb * 16 + lr][lg * 8];
            blf[nb] = *(const bf16x8*)&Bs_l[wc * 64 + nb * 16 + lr][lg * 8];
        }
#pragma unroll
        for (int mb = 0; mb < 2; mb++) {
            bf16x8 ahf = *(const bf16x8*)&As_h[wr * 32 + mb * 16 + lr][lg * 8];
            bf16x8 alf = *(const bf16x8*)&As_l[wr * 32 + mb * 16 + lr][lg * 8];
#pragma unroll
            for (int nb = 0; nb < 4; nb++) {
                f32x4 a = acc[mb][nb];
                a = MFMA(ahf, bhf[nb], a);
                a = MFMA(ahf, blf[nb], a);
                a = MFMA(alf, bhf[nb], a);
                acc[mb][nb] = a;
            }
        }
    }

#pragma unroll
    for (int mb = 0; mb < 2; mb++)
#pragma unroll
        for (int r = 0; r < 4; r++) {
            size_t row = (size_t)(bm + wr * 32 + mb * 16 + lg * 4 + r);
#pragma unroll
            for (int nb = 0; nb < 4; nb++)
                C[row * N + bn + wc * 64 + nb * 16 + lr] = acc[mb][nb][r];
        }
}

// ---------------------------------------------------------------------------
// ws layout (exactly 100 MB, round-2-proven budget):
//   0      QKVG fp32 [4096][4096]  64 MB   (per-head bf16 recycling: Q region
//                                           -> Qh|Ql, K -> Kh|Kl, V -> Yh|Yl)
//   64MB   WTh bf16 [5][1024][1024] 10 MB
//   74MB   WTl bf16 [5][1024][1024] 10 MB
//   84MB   xh -> Vth                 8 MB
//   92MB   xl -> Vtl                 8 MB
// ---------------------------------------------------------------------------
extern "C" void kernel_launch(void* const* d_in, const int* in_sizes, int n_in,
                              void* d_out, int out_size, void* d_ws, size_t ws_size,
                              hipStream_t stream) {
    const float* x   = (const float*)d_in[0];
    const float* Wq  = (const float*)d_in[1];
    const float* Wk  = (const float*)d_in[2];
    const float* Wv  = (const float*)d_in[3];
    const float* Wg  = (const float*)d_in[4];
    const float* Wo  = (const float*)d_in[5];
    const float* gng = (const float*)d_in[6];
    const float* gnb = (const float*)d_in[7];

    char* ws = (char*)d_ws;
    const size_t MB = 1024 * 1024;
    float*          QKVG = (float*)ws;
    unsigned short* WTh  = (unsigned short*)(ws + (size_t)64 * MB);
    unsigned short* WTl  = (unsigned short*)(ws + (size_t)74 * MB);
    unsigned short* Vth  = (unsigned short*)(ws + (size_t)84 * MB);  // xh first
    unsigned short* Vtl  = (unsigned short*)(ws + (size_t)92 * MB);  // xl first
    unsigned short* U    = (unsigned short*)QKVG;

    conv_weights<<<5 * 256, 256, 0, stream>>>(Wq, Wk, Wv, Wg, Wo, WTh, WTl);
    conv_x<<<(ML * D_) / (256 * 4), 256, 0, stream>>>(x, Vth /*xh*/, Vtl /*xl*/);

    // fused projections: [4096,1024] @ [1024,4096] -> QKVG fp32
    gemm_ldst<<<1024, 256, 0, stream>>>(Vth, Vtl, WTh, WTl, QKVG, ML, NBIG, D_, 32);

    // rope+split Q/K into their own regions; V transposed+split into Vth/Vtl
    postproc<<<1024, 256, 0, stream>>>(QKVG, Vth, Vtl);

    retention_v3<<<512, 256, 0, stream>>>(QKVG, Vth, Vtl, gng, gnb);

    // out = Y @ Wo : A = per-head-packed Y inside QKVG
    gemm_out64<<<512, 256, 0, stream>>>(U,
        WTh + (size_t)4 * 1024 * 1024, WTl + (size_t)4 * 1024 * 1024,
        (float*)d_out);
}